// Round 1
// 1491.818 us; speedup vs baseline: 1.0026x; 1.0026x over previous
//
#include <hip/hip_runtime.h>

#define B_ROWS 8192
#define DDIM 1024
#define HDIM 4096
#define H2DIM 2048
#define DOUT_N 1024
#define NEXP 8
#define ROW_TILES 136            // ceil((2*8192 + 8*127)/128) = 136 tiles worst case
#define PAD_ROWS (ROW_TILES*128) // 17408

typedef __attribute__((ext_vector_type(8))) short short8;
typedef __attribute__((ext_vector_type(4))) float f32x4;

// RNE fp32 -> bf16 (finite inputs only)
__device__ inline unsigned short f2bf(float f) {
  unsigned int u = __builtin_bit_cast(unsigned int, f);
  u += 0x7fffu + ((u >> 16) & 1u);
  return (unsigned short)(u >> 16);
}

// async global->LDS, 16B per lane; lds base must be wave-uniform
__device__ inline void gld_lds16(const void* g, void* l) {
  __builtin_amdgcn_global_load_lds(
      (const __attribute__((address_space(1))) void*)g,
      (__attribute__((address_space(3))) void*)l, 16, 0, 0);
}

// counted vmcnt wait (compiler-level memory barrier so loads can't cross)
#define WAITV(N) asm volatile("s_waitcnt vmcnt(" #N ")" ::: "memory")

// raw barrier WITHOUT the __syncthreads vmcnt(0) drain; memory-clobber fences
// stop the compiler moving LDS/global ops across it
__device__ inline void barrier_raw() {
  asm volatile("" ::: "memory");
  __builtin_amdgcn_s_barrier();
  asm volatile("" ::: "memory");
}

// ---------------- gate layer 1: g = relu(x @ Wg1 + bg1), fp32 ----------------
__global__ __launch_bounds__(256) void gate1_kernel(
    const float* __restrict__ x, const float* __restrict__ Wg1,
    const float* __restrict__ bg1, float* __restrict__ g) {
  __shared__ float a_s[16][132];
  __shared__ float b_s[16][64];
  const int t = threadIdx.x;
  const int row0 = blockIdx.y * 128;
  const int n0 = blockIdx.x * 64;
  const int tx = t & 15, ty = t >> 4;
  float c[8][4] = {};
  const int la_row = t >> 2, la_kq = (t & 3) * 4;
  const int lb_kk = t >> 4, lb_c = (t & 15) * 4;
  for (int k0 = 0; k0 < DDIM; k0 += 16) {
#pragma unroll
    for (int i = 0; i < 2; ++i) {
      int row = la_row + i * 64;
      float4 av = *(const float4*)&x[(size_t)(row0 + row) * DDIM + k0 + la_kq];
      a_s[la_kq + 0][row] = av.x; a_s[la_kq + 1][row] = av.y;
      a_s[la_kq + 2][row] = av.z; a_s[la_kq + 3][row] = av.w;
    }
    *(float4*)&b_s[lb_kk][lb_c] = *(const float4*)&Wg1[(size_t)(k0 + lb_kk) * 512 + n0 + lb_c];
    __syncthreads();
#pragma unroll
    for (int kk = 0; kk < 16; ++kk) {
      float4 b4 = *(const float4*)&b_s[kk][tx * 4];
      float4 a4lo = *(const float4*)&a_s[kk][ty * 8];
      float4 a4hi = *(const float4*)&a_s[kk][ty * 8 + 4];
      float aa[8] = {a4lo.x, a4lo.y, a4lo.z, a4lo.w, a4hi.x, a4hi.y, a4hi.z, a4hi.w};
      float bb[4] = {b4.x, b4.y, b4.z, b4.w};
#pragma unroll
      for (int i = 0; i < 8; ++i)
#pragma unroll
        for (int j = 0; j < 4; ++j) c[i][j] += aa[i] * bb[j];
    }
    __syncthreads();
  }
  float bb[4];
#pragma unroll
  for (int j = 0; j < 4; ++j) bb[j] = bg1[n0 + tx * 4 + j];
#pragma unroll
  for (int i = 0; i < 8; ++i) {
    float4 v;
    v.x = fmaxf(c[i][0] + bb[0], 0.f);
    v.y = fmaxf(c[i][1] + bb[1], 0.f);
    v.z = fmaxf(c[i][2] + bb[2], 0.f);
    v.w = fmaxf(c[i][3] + bb[3], 0.f);
    *(float4*)&g[(size_t)(row0 + ty * 8 + i) * 512 + n0 + tx * 4] = v;
  }
}

// ------ gate layer 2 + softmax + top2 + renorm + usage/count accumulation ----
__global__ __launch_bounds__(256) void gate2_kernel(
    const float* __restrict__ g, const float* __restrict__ Wg2,
    const float* __restrict__ bg2, int* __restrict__ top_idx,
    float* __restrict__ top_w, int* __restrict__ counts,
    float* __restrict__ usage) {
  __shared__ float w2t[NEXP * 512];
  __shared__ float us[NEXP];
  __shared__ int cs[NEXP];
  const int t = threadIdx.x;
  for (int i = t; i < NEXP * 512; i += 256) {
    int k = i >> 3, e = i & 7;
    w2t[e * 512 + k] = Wg2[i];
  }
  if (t < NEXP) { us[t] = 0.f; cs[t] = 0; }
  __syncthreads();
  const int lane = t & 63, wid = t >> 6;
  const int row = blockIdx.x * 4 + wid;
  float part[NEXP] = {};
  const float* grow = &g[(size_t)row * 512];
#pragma unroll
  for (int j = 0; j < 8; ++j) {
    int k = lane + j * 64;
    float gv = grow[k];
#pragma unroll
    for (int e = 0; e < NEXP; ++e) part[e] += gv * w2t[e * 512 + k];
  }
#pragma unroll
  for (int e = 0; e < NEXP; ++e)
    for (int m = 32; m >= 1; m >>= 1) part[e] += __shfl_xor(part[e], m);
  if (lane == 0) {
    float p[NEXP];
    float mx = -1e30f;
#pragma unroll
    for (int e = 0; e < NEXP; ++e) { p[e] = part[e] + bg2[e]; mx = fmaxf(mx, p[e]); }
    float s = 0.f;
#pragma unroll
    for (int e = 0; e < NEXP; ++e) { p[e] = expf(p[e] - mx); s += p[e]; }
    float inv = 1.f / s;
#pragma unroll
    for (int e = 0; e < NEXP; ++e) { p[e] *= inv; atomicAdd(&us[e], p[e]); }
    int i0 = 0; float b0 = p[0];
    for (int e = 1; e < NEXP; ++e) if (p[e] > b0) { b0 = p[e]; i0 = e; }
    int i1 = -1; float b1 = -1.f;
    for (int e = 0; e < NEXP; ++e) {
      if (e == i0) continue;
      if (p[e] > b1) { b1 = p[e]; i1 = e; }
    }
    float e1 = expf(b1 - b0);
    float w0 = 1.f / (1.f + e1);
    top_idx[row * 2 + 0] = i0; top_idx[row * 2 + 1] = i1;
    top_w[row * 2 + 0] = w0;   top_w[row * 2 + 1] = e1 * w0;
    atomicAdd(&cs[i0], 1); atomicAdd(&cs[i1], 1);
  }
  __syncthreads();
  if (t < NEXP) { atomicAdd(&usage[t], us[t]); atomicAdd(&counts[t], cs[t]); }
}

// --------- offsets: 128-aligned segment starts per expert --------------------
__global__ void offsets_kernel(const int* __restrict__ counts, int* __restrict__ off) {
  if (threadIdx.x == 0) {
    int acc = 0;
    off[0] = 0;
    for (int e = 0; e < NEXP; ++e) {
      acc += (counts[e] + 127) & ~127;
      off[e + 1] = acc;
    }
  }
}

// --------- scatter rows into per-expert entry lists + inverse map ------------
__global__ __launch_bounds__(256) void scatter_kernel(
    const int* __restrict__ top_idx, const int* __restrict__ off,
    int* __restrict__ fill, int* __restrict__ entry, int* __restrict__ posof) {
  int row = blockIdx.x * 256 + threadIdx.x;
#pragma unroll
  for (int k = 0; k < 2; ++k) {
    int e = top_idx[row * 2 + k];
    int pos = atomicAdd(&fill[e], 1);
    entry[off[e] + pos] = row * 2 + k;
    posof[row * 2 + k] = off[e] + pos;
  }
}

// --------- gather x rows (fp32) -> dense bf16 A matrix by entry position -----
__global__ __launch_bounds__(256) void gather_kernel(
    const float* __restrict__ x, const int* __restrict__ entry,
    unsigned short* __restrict__ Xg) {
  const int r = blockIdx.x;
  const int s = entry[r];
  const int t = threadIdx.x;
  unsigned long long packed = 0ull;
  if (s >= 0) {
    float4 f = *(const float4*)&x[(size_t)(s >> 1) * DDIM + t * 4];
    packed = (unsigned long long)f2bf(f.x) |
             ((unsigned long long)f2bf(f.y) << 16) |
             ((unsigned long long)f2bf(f.z) << 32) |
             ((unsigned long long)f2bf(f.w) << 48);
  }
  *(unsigned long long*)&Xg[(size_t)r * DDIM + t * 4] = packed;
}

// --------- weight transpose+convert: [K][N] fp32 -> [N][K] bf16 per expert ---
__global__ __launch_bounds__(256) void transpose_kernel(
    const float* __restrict__ src, unsigned short* __restrict__ dst,
    int K, int N) {
  __shared__ float tile[64][65];
  const size_t eoff = (size_t)blockIdx.z * K * N;
  const int k0 = blockIdx.y * 64, n0 = blockIdx.x * 64;
  const int t = threadIdx.x;
#pragma unroll
  for (int i = 0; i < 16; ++i) {
    int idx = t + i * 256;
    int kk = idx >> 6, nn = idx & 63;
    tile[kk][nn] = src[eoff + (size_t)(k0 + kk) * N + n0 + nn];
  }
  __syncthreads();
#pragma unroll
  for (int i = 0; i < 16; ++i) {
    int idx = t + i * 256;
    int nn = idx >> 6, kk = idx & 63;
    dst[eoff + (size_t)(n0 + nn) * K + k0 + kk] = f2bf(tile[kk][nn]);
  }
}

// ---------------- expert GEMM: deep-pipelined 8-wave 128x256 tile ------------
// A: [PAD_ROWS][KDIM] bf16 by entry pos; Bt: [E][N][KDIM] bf16.
// 512 thr = 8 waves (2M x 4N), per-wave 64x64 (4x4 frags of 16x16x32).
// K pipelined in BK=32 sub-tiles: 4 LDS buffers (96 KiB), prefetch depth 3,
// raw s_barrier + counted vmcnt (2 sub-tiles stay in flight across barriers),
// XOR-swizzled LDS (2-way bank aliasing = free), setprio around MFMA.
// EPI 0: relu(acc+bias) -> bf16 Cout ; EPI 1: (acc+bias) -> f32 Eo (positional)
template <int KDIM, int EPI>
__global__ __launch_bounds__(512, 2) void expert_gemm(
    const unsigned short* __restrict__ A, const unsigned short* __restrict__ Bt,
    const float* __restrict__ bias, unsigned short* __restrict__ Cout,
    float* __restrict__ Eo, const int* __restrict__ off, int N) {
  constexpr int NS = KDIM / 32;  // sub-tiles
  static_assert(NS >= 4, "need >=4 K sub-tiles");
  __shared__ unsigned short smem[4 * 12288];  // 4 bufs x (A 128x32 + B 256x32)

  // XCD-aware bijective block swizzle (grid counts are all %8==0)
  const int gx = gridDim.x;
  const int nwg = gx * gridDim.y;
  const int orig = blockIdx.x + gx * blockIdx.y;
  const int cpx = nwg >> 3;
  const int swz = (orig & 7) * cpx + (orig >> 3);
  const int tm = swz / gx, tn = swz - tm * gx;
  const int tileM = tm * 128;
  if (tileM >= off[NEXP]) return;  // uniform exit, before any barrier
  int e = 0;
  while (e < NEXP - 1 && off[e + 1] <= tileM) ++e;
  const int tileN = tn * 256;

  const int t = threadIdx.x;
  const int lane = t & 63, wid = t >> 6;
  const int wr = (wid >> 2) * 64;   // wave row base in [0,128)
  const int wc = (wid & 3) * 64;    // wave col base in [0,256)
  const int l16 = lane & 15, q = lane >> 4;

  const unsigned short* Abase = A + (size_t)tileM * KDIM;
  const unsigned short* Bbase = Bt + ((size_t)e * N + tileN) * (size_t)KDIM;

  // staging geometry: per sub-tile 1 A-load + 2 B-loads per thread (16B each)
  const int srow0 = wid * 16 + (lane >> 2);  // 0..127
  const int scp = lane & 3;                  // dest 16B chunk within row

  f32x4 acc[4][4];
#pragma unroll
  for (int i = 0; i < 4; ++i)
#pragma unroll
    for (int j = 0; j < 4; ++j) acc[i][j] = (f32x4){0.f, 0.f, 0.f, 0.f};

  // LDS holds swizzled layout: chunk c of row r lives at chunk c^((r>>1)&3).
  // global_load_lds writes linearly -> pre-swizzle the GLOBAL source chunk.
  auto stage = [&](int s) {
    unsigned short* buf = &smem[(size_t)(s & 3) * 12288];
    const int k0 = s * 32;
    {
      const int row = srow0;
      const int c = scp ^ ((row >> 1) & 3);
      gld_lds16(Abase + (size_t)row * KDIM + k0 + c * 8,
                buf + (size_t)(wid * 16) * 32);
    }
#pragma unroll
    for (int j = 0; j < 2; ++j) {
      const int row = j * 128 + srow0;
      const int c = scp ^ ((row >> 1) & 3);
      gld_lds16(Bbase + (size_t)row * KDIM + k0 + c * 8,
                buf + 4096 + (size_t)(j * 128 + wid * 16) * 32);
    }
  };

  auto rdfrags = [&](int s, short8* af, short8* bf) {
    const unsigned short* buf = &smem[(size_t)(s & 3) * 12288];
#pragma unroll
    for (int i = 0; i < 4; ++i) {
      const int row = wr + 16 * i + l16;
      const int c = q ^ ((row >> 1) & 3);
      af[i] = *(const short8*)&buf[row * 32 + c * 8];
    }
#pragma unroll
    for (int j = 0; j < 4; ++j) {
      const int row = wc + 16 * j + l16;
      const int c = q ^ ((row >> 1) & 3);
      bf[j] = *(const short8*)&buf[4096 + row * 32 + c * 8];
    }
  };

  auto domfma = [&](short8* af, short8* bf) {
    __builtin_amdgcn_s_setprio(1);
#pragma unroll
    for (int i = 0; i < 4; ++i)
#pragma unroll
      for (int j = 0; j < 4; ++j)
        acc[i][j] = __builtin_amdgcn_mfma_f32_16x16x32_bf16(af[i], bf[j], acc[i][j], 0, 0, 0);
    __builtin_amdgcn_s_setprio(0);
  };

  // prologue: 3 sub-tiles in flight; publish buf0 (oldest 3 loads) only
  stage(0); stage(1); stage(2);
  WAITV(6);
  barrier_raw();

  // main loop: stage(s+3), compute(s), publish s+1 with 2 sub-tiles (6 loads)
  // still in flight -> loads survive the barrier (counted vmcnt, never 0)
#pragma unroll 4
  for (int s = 0; s < NS - 3; ++s) {
    short8 af[4], bf[4];
    rdfrags(s, af, bf);
    stage(s + 3);
    domfma(af, bf);
    WAITV(6);
    barrier_raw();
  }
  {  // s = NS-3: only stages NS-2, NS-1 outstanding (6) -> wait to 3
    short8 af[4], bf[4];
    rdfrags(NS - 3, af, bf);
    domfma(af, bf);
    WAITV(3);
    barrier_raw();
  }
  {  // s = NS-2: drain the last stage
    short8 af[4], bf[4];
    rdfrags(NS - 2, af, bf);
    domfma(af, bf);
    WAITV(0);
    barrier_raw();
  }
  {  // s = NS-1
    short8 af[4], bf[4];
    rdfrags(NS - 1, af, bf);
    domfma(af, bf);
  }

  if (EPI == 0) {
#pragma unroll
    for (int j = 0; j < 4; ++j) {
      const int gCol = tileN + wc + 16 * j + l16;
      const float bcol = bias[e * N + gCol];
#pragma unroll
      for (int i = 0; i < 4; ++i) {
        const int gRow0 = tileM + wr + 16 * i + q * 4;
#pragma unroll
        for (int r = 0; r < 4; ++r)
          Cout[(size_t)(gRow0 + r) * N + gCol] = f2bf(fmaxf(acc[i][j][r] + bcol, 0.f));
      }
    }
  } else {
    float bcol[4];
#pragma unroll
    for (int j = 0; j < 4; ++j) bcol[j] = bias[e * N + tileN + wc + 16 * j + l16];
#pragma unroll
    for (int i = 0; i < 4; ++i) {
      const int gRow0 = tileM + wr + 16 * i + q * 4;
#pragma unroll
      for (int r = 0; r < 4; ++r) {
        float* orow = Eo + (size_t)(gRow0 + r) * N;
#pragma unroll
        for (int j = 0; j < 4; ++j)
          orow[tileN + wc + 16 * j + l16] = acc[i][j][r] + bcol[j];
      }
    }
  }
}

// --------- combine: out[row] = w0*eo[pos0] + w1*eo[pos1] (coalesced) ---------
__global__ __launch_bounds__(256) void combine_kernel(
    const float* __restrict__ eo, const int* __restrict__ posof,
    const float* __restrict__ tw, float* __restrict__ out) {
  const int row = blockIdx.x;
  const int c = threadIdx.x * 4;
  const int p0 = posof[row * 2 + 0], p1 = posof[row * 2 + 1];
  const float w0 = tw[row * 2 + 0], w1 = tw[row * 2 + 1];
  float4 a = *(const float4*)&eo[(size_t)p0 * DOUT_N + c];
  float4 b = *(const float4*)&eo[(size_t)p1 * DOUT_N + c];
  float4 o;
  o.x = w0 * a.x + w1 * b.x;
  o.y = w0 * a.y + w1 * b.y;
  o.z = w0 * a.z + w1 * b.z;
  o.w = w0 * a.w + w1 * b.w;
  *(float4*)&out[(size_t)row * DOUT_N + c] = o;
}

// ---------------- load-balance loss ------------------------------------------
__global__ void loss_kernel(const float* __restrict__ usage, float* __restrict__ out) {
  if (threadIdx.x == 0) {
    float l = 0.f;
    for (int e = 0; e < NEXP; ++e) {
      float d = usage[e] * (1.f / B_ROWS) - 1.f / NEXP;
      l += d * d;
    }
    out[(size_t)B_ROWS * DOUT_N] = l * (1.f / NEXP);
  }
}

extern "C" void kernel_launch(void* const* d_in, const int* in_sizes, int n_in,
                              void* d_out, int out_size, void* d_ws, size_t ws_size,
                              hipStream_t stream) {
  (void)in_sizes; (void)n_in; (void)ws_size;
  const float* x   = (const float*)d_in[0];
  const float* W1  = (const float*)d_in[1];
  const float* b1  = (const float*)d_in[2];
  const float* W2  = (const float*)d_in[3];
  const float* b2  = (const float*)d_in[4];
  const float* W3  = (const float*)d_in[5];
  const float* b3  = (const float*)d_in[6];
  const float* Wg1 = (const float*)d_in[7];
  const float* bg1 = (const float*)d_in[8];
  const float* Wg2 = (const float*)d_in[9];
  const float* bg2 = (const float*)d_in[10];
  float* out = (float*)d_out;

  char* ws = (char*)d_ws;
  size_t p = 0;
  auto alloc = [&](size_t bytes) {
    void* r = ws + p;
    p = (p + bytes + 255) & ~(size_t)255;
    return r;
  };
  int*   off    = (int*)alloc(9 * 4);
  int*   counts = (int*)alloc(NEXP * 4);
  int*   fill   = (int*)alloc(NEXP * 4);
  float* usage  = (float*)alloc(NEXP * 4);
  int*   tidx   = (int*)alloc((size_t)B_ROWS * 2 * 4);
  float* tw     = (float*)alloc((size_t)B_ROWS * 2 * 4);
  int*   posof  = (int*)alloc((size_t)B_ROWS * 2 * 4);
  int*   entry  = (int*)alloc((size_t)PAD_ROWS * 4);
  float* g      = (float*)alloc((size_t)B_ROWS * 512 * 4);
  unsigned short* Xg  = (unsigned short*)alloc((size_t)PAD_ROWS * DDIM * 2);
  unsigned short* W1t = (unsigned short*)alloc((size_t)NEXP * HDIM * DDIM * 2);
  unsigned short* W2t = (unsigned short*)alloc((size_t)NEXP * H2DIM * HDIM * 2);
  unsigned short* W3t = (unsigned short*)alloc((size_t)NEXP * DOUT_N * H2DIM * 2);
  unsigned short* h1  = (unsigned short*)alloc((size_t)PAD_ROWS * HDIM * 2);
  unsigned short* h2  = (unsigned short*)alloc((size_t)PAD_ROWS * H2DIM * 2);
  // eo [PAD_ROWS][DOUT_N] f32 (71.3MB) aliases h1 (142.6MB): h1 is dead after
  // GEMM2 reads it; GEMM3 (which writes eo) reads only h2. ~501 MB total.
  float* eo = (float*)h1;

  hipMemsetAsync(d_out, 0, (size_t)out_size * 4, stream);
  hipMemsetAsync(counts, 0, NEXP * 4, stream);
  hipMemsetAsync(fill, 0, NEXP * 4, stream);
  hipMemsetAsync(usage, 0, NEXP * 4, stream);
  hipMemsetAsync(entry, 0xFF, (size_t)PAD_ROWS * 4, stream);

  // weight transpose+convert (independent of routing)
  transpose_kernel<<<dim3(HDIM / 64, DDIM / 64, NEXP), 256, 0, stream>>>(W1, W1t, DDIM, HDIM);
  transpose_kernel<<<dim3(H2DIM / 64, HDIM / 64, NEXP), 256, 0, stream>>>(W2, W2t, HDIM, H2DIM);
  transpose_kernel<<<dim3(DOUT_N / 64, H2DIM / 64, NEXP), 256, 0, stream>>>(W3, W3t, H2DIM, DOUT_N);

  // gate (fp32 exact) + routing
  gate1_kernel<<<dim3(512 / 64, B_ROWS / 128), 256, 0, stream>>>(x, Wg1, bg1, g);
  gate2_kernel<<<B_ROWS / 4, 256, 0, stream>>>(g, Wg2, bg2, tidx, tw, counts, usage);
  offsets_kernel<<<1, 64, 0, stream>>>(counts, off);
  scatter_kernel<<<B_ROWS / 256, 256, 0, stream>>>(tidx, off, fill, entry, posof);
  gather_kernel<<<PAD_ROWS, 256, 0, stream>>>(x, entry, Xg);

  // routed expert MLP (bf16 MFMA, deep-pipelined 128x256 tiles)
  expert_gemm<DDIM, 0><<<dim3(HDIM / 256, ROW_TILES), 512, 0, stream>>>(
      Xg, W1t, b1, h1, nullptr, off, HDIM);
  expert_gemm<HDIM, 0><<<dim3(H2DIM / 256, ROW_TILES), 512, 0, stream>>>(
      h1, W2t, b2, h2, nullptr, off, H2DIM);
  expert_gemm<H2DIM, 1><<<dim3(DOUT_N / 256, ROW_TILES), 512, 0, stream>>>(
      h2, W3t, b3, nullptr, eo, off, DOUT_N);
  combine_kernel<<<B_ROWS, 256, 0, stream>>>(eo, posof, tw, out);

  loss_kernel<<<1, 64, 0, stream>>>(usage, out);
}